// Round 10
// baseline (170.296 us; speedup 1.0000x reference)
//
#include <hip/hip_runtime.h>

#define DD 160

// ============ K1 body: x-pass sliding window (one scale) ============
// in/tg raw [B][160][160][160] -> xb 5 channels [ch][b][x'][y][z].
// NCH parity chains (2 for odd S); slide step NCH*S even -> remove/add R taps.
template<int N, int K, int S, int NCH, int CL>
__device__ __forceinline__ void k1_body(
    const float* __restrict__ in, const float* __restrict__ tg,
    float* __restrict__ xb, int B, long t) {
    const long XS = (long)DD * DD;
    const long P  = (long)B * XS;
    constexpr int NPC0 = (N + NCH - 1) / NCH;
    constexpr int CC   = (NPC0 + CL - 1) / CL;
    constexpr int R    = (NCH * S) / 2;
    if (t >= P * NCH * CC) return;
    long p = t % P;
    int  r = (int)(t / P);
    int chain  = r % NCH;
    int cchunk = r / NCH;
    int b = (int)(p / XS);
    long yz = p % XS;
    const float* ia = in + (long)b * DD * XS + yz;
    const float* ta = tg + (long)b * DD * XS + yz;
    const long CH = (long)B * N * XS;
    float* ob = xb + (long)b * N * XS + yz;

    const int npc = (N - chain + NCH - 1) / NCH;
    int j0 = cchunk * CL;
    if (j0 >= npc) return;
    int xp = chain + j0 * NCH;
    int x0 = xp * S;
    float s0 = 0.f, s1 = 0.f, s2 = 0.f, s3 = 0.f, s4 = 0.f;

    constexpr int G = (K >= 16) ? 8 : K;
#pragma unroll
    for (int g = 0; g < K; g += G) {
        float u[G], w[G];
#pragma unroll
        for (int j = 0; j < G; ++j)
            if (g + j < K) {
                u[j] = ia[(long)(x0 + 2 * (g + j)) * XS];
                w[j] = ta[(long)(x0 + 2 * (g + j)) * XS];
            }
#pragma unroll
        for (int j = 0; j < G; ++j)
            if (g + j < K) {
                s0 += u[j]; s1 += w[j]; s2 += u[j] * u[j];
                s3 += w[j] * w[j]; s4 += u[j] * w[j];
            }
    }
    {
        long oo = (long)xp * XS;
        ob[oo] = s0; ob[oo + CH] = s1; ob[oo + 2 * CH] = s2;
        ob[oo + 3 * CH] = s3; ob[oo + 4 * CH] = s4;
    }
#pragma unroll
    for (int q = 1; q < CL; ++q) {
        if (j0 + q >= npc) break;
        float ru[R], rw[R], au[R], aw[R];
#pragma unroll
        for (int j = 0; j < R; ++j) {
            ru[j] = ia[(long)(x0 + 2 * j) * XS];
            rw[j] = ta[(long)(x0 + 2 * j) * XS];
            au[j] = ia[(long)(x0 + 2 * K + 2 * j) * XS];
            aw[j] = ta[(long)(x0 + 2 * K + 2 * j) * XS];
        }
#pragma unroll
        for (int j = 0; j < R; ++j) {
            s0 += au[j] - ru[j];
            s1 += aw[j] - rw[j];
            s2 += au[j] * au[j] - ru[j] * ru[j];
            s3 += aw[j] * aw[j] - rw[j] * rw[j];
            s4 += au[j] * aw[j] - ru[j] * rw[j];
        }
        xp += NCH;
        x0 += NCH * S;
        long oo = (long)xp * XS;
        ob[oo] = s0; ob[oo + CH] = s1; ob[oo + 2 * CH] = s2;
        ob[oo + 3 * CH] = s3; ob[oo + 4 * CH] = s4;
    }
}

// All three scales, one dispatch. s2/s1 (long-serial threads) first.
__global__ __launch_bounds__(256) void k1all(
    const float* __restrict__ in, const float* __restrict__ tg,
    float* __restrict__ xb0, float* __restrict__ xb1, float* __restrict__ xb2,
    int B, int nb2, int nb1) {
    int bid = blockIdx.x;
    if (bid < nb2) {
        k1_body<9, 40, 10, 1, 5>(in, tg, xb2, B, (long)bid * 256 + threadIdx.x);
    } else if (bid < nb2 + nb1) {
        k1_body<25, 20, 5, 2, 7>(in, tg, xb1, B, (long)(bid - nb2) * 256 + threadIdx.x);
    } else {
        k1_body<71, 10, 2, 1, 12>(in, tg, xb0, B,
                                  (long)(bid - nb2 - nb1) * 256 + threadIdx.x);
    }
}

// ============ K23 chain body: y-sliding fused y-window + z-scan + LNCC ======
// One WAVE owns a chain of CL same-parity yp rows of one (b,x') slab.
// Init: K column loads/channel; slide: R removes + R adds (R = NCH*S/2).
// Per row: parity prefix scan along z, window-diff -> LNCC; wave-accumulate.
template<int N, int K, int S, int NCH, int CL>
__device__ __forceinline__ void k23c(
    const float* __restrict__ xb, float* __restrict__ acc, int B, long task,
    float* Sw, float* wsum) {
    constexpr int NPC0 = (N + NCH - 1) / NCH;
    constexpr int CC   = (NPC0 + CL - 1) / CL;
    constexpr int R    = (NCH * S) / 2;
    constexpr float numel = (float)K * K * K;
    const int tid = threadIdx.x, wid = tid >> 6, lane = tid & 63;
    const long XS = (long)DD * DD;
    const long CH = (long)B * N * XS;
    const long T  = (long)B * N * NCH * CC;
    float v = 0.f;
    if (task < T) {
        int chunk = (int)(task % CC); long r = task / CC;
        int chain = (int)(r % NCH); r /= NCH;
        int xp = (int)(r % N);
        int b  = (int)(r / N);
        const float* sbase = xb + ((long)b * N + xp) * XS;
        const int lane2 = (lane < 32) ? lane + 128 : lane + 64;  // dummy in-bounds
        float st0[5], st1[5], st2[5];
        const int y0 = chain + chunk * CL * NCH;
#pragma unroll
        for (int q = 0; q < CL; ++q) {
            int yp = y0 + q * NCH;
            if (yp >= N) break;
            int cb = yp * S;
            if (q == 0) {
#pragma unroll
                for (int ch = 0; ch < 5; ++ch) {
                    const float* cp = sbase + (long)ch * CH + (long)cb * DD;
                    float a0 = 0.f, a1 = 0.f, a2 = 0.f;
                    constexpr int G = (K > 10) ? 10 : K;
#pragma unroll
                    for (int g = 0; g < K; g += G) {
                        float t0[G], t1[G], t2[G];
#pragma unroll
                        for (int j = 0; j < G; ++j)
                            if (g + j < K) {
                                const float* pp = cp + (long)(2 * (g + j)) * DD;
                                t0[j] = pp[lane];
                                t1[j] = pp[lane + 64];
                                t2[j] = pp[lane2];
                            }
#pragma unroll
                        for (int j = 0; j < G; ++j)
                            if (g + j < K) { a0 += t0[j]; a1 += t1[j]; a2 += t2[j]; }
                    }
                    st0[ch] = a0; st1[ch] = a1; st2[ch] = a2;
                }
            } else {
                const int pb = cb - NCH * S;
#pragma unroll
                for (int ch = 0; ch < 5; ++ch) {
                    const float* cp = sbase + (long)ch * CH;
                    float r0[R], r1[R], r2[R], a0[R], a1[R], a2[R];
#pragma unroll
                    for (int j = 0; j < R; ++j) {
                        const float* rp = cp + (long)(pb + 2 * j) * DD;
                        const float* ap = cp + (long)(pb + 2 * K + 2 * j) * DD;
                        r0[j] = rp[lane]; r1[j] = rp[lane + 64]; r2[j] = rp[lane2];
                        a0[j] = ap[lane]; a1[j] = ap[lane + 64]; a2[j] = ap[lane2];
                    }
                    float d0 = 0.f, d1 = 0.f, d2 = 0.f;
#pragma unroll
                    for (int j = 0; j < R; ++j) {
                        d0 += a0[j] - r0[j];
                        d1 += a1[j] - r1[j];
                        d2 += a2[j] - r2[j];
                    }
                    st0[ch] += d0; st1[ch] += d1; st2[ch] += d2;
                }
            }
            // per-row: parity prefix scan per channel -> Sw, then LNCC
#pragma unroll
            for (int ch = 0; ch < 5; ++ch) {
                float v0 = st0[ch], v1 = st1[ch];
                float v2 = (lane < 32) ? st2[ch] : 0.f;
#pragma unroll
                for (int o = 2; o <= 32; o <<= 1) {
                    float q0 = __shfl_up(v0, o);
                    float q1 = __shfl_up(v1, o);
                    float q2 = __shfl_up(v2, o);
                    if (lane >= o) { v0 += q0; v1 += q1; v2 += q2; }
                }
                float c1 = __shfl(v0, 62 + (lane & 1)); v1 += c1;
                float c2 = __shfl(v1, 62 + (lane & 1)); v2 += c2;
                float* outp = Sw + ch * 162;
                if (lane < 2) outp[lane] = 0.f;
                outp[lane + 2]  = v0;
                outp[lane + 66] = v1;
                if (lane < 32) outp[lane + 130] = v2;
            }
#pragma unroll
            for (int t = lane; t < N; t += 64) {
                int lo = t * S, hi = lo + 2 * K;
                float a0 = Sw[0 * 162 + hi] - Sw[0 * 162 + lo];
                float a1 = Sw[1 * 162 + hi] - Sw[1 * 162 + lo];
                float a2 = Sw[2 * 162 + hi] - Sw[2 * 162 + lo];
                float a3 = Sw[3 * 162 + hi] - Sw[3 * 162 + lo];
                float a4 = Sw[4 * 162 + hi] - Sw[4 * 162 + lo];
                float xm = a0 / numel, ym = a1 / numel;
                float cross = a4 - ym * a0 - xm * a1 + ym * xm * numel;
                float xvar  = a2 - 2.f * xm * a0 + xm * xm * numel;
                float yvar  = a3 - 2.f * ym * a1 + ym * ym * numel;
                v += cross * cross / (xvar * yvar + 1e-5f);
            }
        }
    }
    for (int o = 32; o > 0; o >>= 1) v += __shfl_down(v, o, 64);
    if (lane == 0) wsum[wid] = v;
    __syncthreads();
    if (tid == 0) atomicAdd(acc, wsum[0] + wsum[1] + wsum[2] + wsum[3]);
}

// Segments: s2 [0,b2), s1 [b2,b2+b1), s0 rest (XCD-swizzled, bijective).
__global__ __launch_bounds__(256) void k23all(
    const float* __restrict__ xb0, const float* __restrict__ xb1,
    const float* __restrict__ xb2, float* __restrict__ acc,
    int B, int b2, int b1, int b0) {
    __shared__ float Sm[4][5][162];
    __shared__ float wsum[4];
    const int wid = threadIdx.x >> 6;
    float* Sw = &Sm[wid][0][0];
    int bid = blockIdx.x;
    if (bid < b2) {
        k23c<9, 40, 10, 1, 3>(xb2, acc + 2, B, (long)bid * 4 + wid, Sw, wsum);
    } else if (bid < b2 + b1) {
        k23c<25, 20, 5, 2, 4>(xb1, acc + 1, B, (long)(bid - b2) * 4 + wid, Sw, wsum);
    } else {
        int local = bid - b2 - b1;
        int q = b0 >> 3, r8 = b0 & 7;
        int xcd = local & 7, idx = local >> 3;
        int swz = (xcd < r8) ? xcd * (q + 1) + idx
                             : r8 * (q + 1) + (xcd - r8) * q + idx;
        k23c<71, 10, 2, 1, 6>(xb0, acc + 0, B, (long)swz * 4 + wid, Sw, wsum);
    }
}

__global__ void finalize_kernel(const float* __restrict__ acc, float* __restrict__ out,
                                float c0, float c1, float c2,
                                float w0, float w1, float w2) {
    if (threadIdx.x == 0 && blockIdx.x == 0) {
        out[0] = w0 * (1.f - acc[0] / c0) +
                 w1 * (1.f - acc[1] / c1) +
                 w2 * (1.f - acc[2] / c2);
    }
}

extern "C" void kernel_launch(void* const* d_in, const int* in_sizes, int n_in,
                              void* d_out, int out_size, void* d_ws, size_t ws_size,
                              hipStream_t stream) {
    const float* input  = (const float*)d_in[0];
    const float* target = (const float*)d_in[1];
    float* out = (float*)d_out;

    char* ws = (char*)d_ws;
    float* acc = (float*)ws;
    const size_t accPad = 256;
    const long XS = (long)DD * DD;

    // full-batch (NB=2) need: 5*2*(71+25+9)*25600 floats = ~107.5 MB
    const size_t fullNeed = accPad + 5ull * 2 * 105 * XS * sizeof(float);
    const int NB = (ws_size >= fullNeed) ? 2 : 1;

    float* xb0 = (float*)(ws + accPad);
    float* xb1 = xb0 + 5ull * NB * 71 * XS;
    float* xb2 = xb1 + 5ull * NB * 25 * XS;

    hipMemsetAsync(acc, 0, 3 * sizeof(float), stream);

    for (int b0i = 0; b0i < 2; b0i += NB) {
        const float* ip = input  + (size_t)b0i * DD * XS;
        const float* tp = target + (size_t)b0i * DD * XS;
        // k1 blocks per scale: s0 600*NB (CC=6), s1 400*NB (NCH*CC=4), s2 200*NB (CC=2)
        const int nb0 = 600 * NB, nb1 = 400 * NB, nb2 = 200 * NB;
        k1all<<<dim3(nb2 + nb1 + nb0), dim3(256), 0, stream>>>(
            ip, tp, xb0, xb1, xb2, NB, nb2, nb1);
        // k23 chain-tasks: s0 N=71,CL=6 -> CC=12; s1 N=25,NCH=2,CL=4 -> CC=4; s2 N=9,CL=3 -> CC=3
        const int T0 = NB * 71 * 12, T1 = NB * 25 * 2 * 4, T2 = NB * 9 * 3;
        const int b2 = (T2 + 3) / 4, b1 = (T1 + 3) / 4, b0 = (T0 + 3) / 4;
        k23all<<<dim3(b2 + b1 + b0), dim3(256), 0, stream>>>(
            xb0, xb1, xb2, acc, NB, b2, b1, b0);
    }
    finalize_kernel<<<dim3(1), dim3(64), 0, stream>>>(
        acc, out,
        2.f * 71.f * 71.f * 71.f,
        2.f * 25.f * 25.f * 25.f,
        2.f * 9.f * 9.f * 9.f,
        0.1f, 0.3f, 0.6f);
}